// Round 1
// baseline (1088.379 us; speedup 1.0000x reference)
//
#include <hip/hip_runtime.h>
#include <math.h>

#define H 128
#define IN1 258
#define STR1 260   // padded LDS row stride (floats) so float4 stores stay 16B-aligned
#define TE 32      // edges per block
#define TN 32      // nodes per block

__device__ __forceinline__ float silu_f(float x) {
    return x / (1.0f + __expf(-x));
}

// -------------------- edge kernel --------------------
__global__ __launch_bounds__(256) void edge_kernel(
    const float* __restrict__ h, const int* __restrict__ ei,
    const float* __restrict__ coord, const float* __restrict__ eattr,
    const float* __restrict__ eW1, const float* __restrict__ eb1,
    const float* __restrict__ eg1, const float* __restrict__ ebe1,
    const float* __restrict__ eW2, const float* __restrict__ eb2,
    const float* __restrict__ eg2, const float* __restrict__ ebe2,
    const float* __restrict__ cW1, const float* __restrict__ cb1,
    const float* __restrict__ cg1, const float* __restrict__ cbe1,
    const float* __restrict__ cW2,
    float* __restrict__ agg, float* __restrict__ coord_out,
    int E)
{
    __shared__ float inp_s[TE * STR1];   // 33,280 B
    __shared__ float buf_s[TE * H];      // 16,384 B  (x, then edge_feat)
    __shared__ float cd_s[TE * 3];
    __shared__ int   row_s[TE];
    __shared__ int   col_s[TE];

    const int t = threadIdx.x;

    // ---- stage inputs: 8 threads per edge ----
    {
        const int e = t >> 3, j = t & 7;
        int ge = blockIdx.x * TE + e;
        int gec = (ge < E) ? ge : 0;
        int row = ei[gec], col = ei[E + gec];
        if (j == 0) { row_s[e] = row; col_s[e] = col; }
        const float4* hr = (const float4*)(h + (size_t)row * H);
        const float4* hc = (const float4*)(h + (size_t)col * H);
        #pragma unroll
        for (int i = 0; i < 4; ++i) {
            *(float4*)&inp_s[e * STR1 + 4 * (j + 8 * i)]     = hr[j + 8 * i];
            *(float4*)&inp_s[e * STR1 + H + 4 * (j + 8 * i)] = hc[j + 8 * i];
        }
    }
    __syncthreads();
    if (t < TE) {
        int r = row_s[t], c = col_s[t];
        float dx = coord[r * 3 + 0] - coord[c * 3 + 0];
        float dy = coord[r * 3 + 1] - coord[c * 3 + 1];
        float dz = coord[r * 3 + 2] - coord[c * 3 + 2];
        float radial = dx * dx + dy * dy + dz * dz;
        float inv = 1.0f / (sqrtf(radial + 1e-8f) + 1.0f);
        cd_s[t * 3 + 0] = dx * inv;
        cd_s[t * 3 + 1] = dy * inv;
        cd_s[t * 3 + 2] = dz * inv;
        int geh = blockIdx.x * TE + t;
        inp_s[t * STR1 + 256] = radial;
        inp_s[t * STR1 + 257] = (geh < E) ? eattr[geh] : 0.0f;
    }
    __syncthreads();

    // compute-phase mapping: thread = (cc in [0,32), ceb in [0,8))
    // handles cols 4cc..4cc+3  x  edges {ceb, ceb+8, ceb+16, ceb+24}
    const int cc = t & 31, ceb = t >> 5;

    // ---- GEMM1: inp(32x258) @ eW1(258x128) ----
    float acc[4][4];
    #pragma unroll
    for (int q = 0; q < 4; ++q)
        for (int jj = 0; jj < 4; ++jj) acc[q][jj] = 0.0f;

    for (int k = 0; k < IN1; ++k) {
        float4 wv = *(const float4*)(eW1 + (size_t)k * H + 4 * cc);
        #pragma unroll
        for (int q = 0; q < 4; ++q) {
            float a = inp_s[(ceb + 8 * q) * STR1 + k];
            acc[q][0] += a * wv.x; acc[q][1] += a * wv.y;
            acc[q][2] += a * wv.z; acc[q][3] += a * wv.w;
        }
    }

    // ---- bias + LN + SiLU -> buf_s (x) ----
    {
        float4 bv  = *(const float4*)(eb1 + 4 * cc);
        float4 gv  = *(const float4*)(eg1 + 4 * cc);
        float4 bev = *(const float4*)(ebe1 + 4 * cc);
        #pragma unroll
        for (int q = 0; q < 4; ++q) {
            float x0 = acc[q][0] + bv.x, x1 = acc[q][1] + bv.y;
            float x2 = acc[q][2] + bv.z, x3 = acc[q][3] + bv.w;
            float s  = x0 + x1 + x2 + x3;
            float ss = x0 * x0 + x1 * x1 + x2 * x2 + x3 * x3;
            #pragma unroll
            for (int m = 1; m <= 16; m <<= 1) {
                s  += __shfl_xor(s, m, 64);
                ss += __shfl_xor(ss, m, 64);
            }
            float mu   = s * (1.0f / 128.0f);
            float var  = ss * (1.0f / 128.0f) - mu * mu;
            float rstd = rsqrtf(var + 1e-5f);
            float* dst = &buf_s[(ceb + 8 * q) * H + 4 * cc];
            dst[0] = silu_f((x0 - mu) * rstd * gv.x + bev.x);
            dst[1] = silu_f((x1 - mu) * rstd * gv.y + bev.y);
            dst[2] = silu_f((x2 - mu) * rstd * gv.z + bev.z);
            dst[3] = silu_f((x3 - mu) * rstd * gv.w + bev.w);
        }
    }
    __syncthreads();

    // ---- GEMM2: x(32x128) @ eW2(128x128) ----
    float a2[4][4];
    #pragma unroll
    for (int q = 0; q < 4; ++q)
        for (int jj = 0; jj < 4; ++jj) a2[q][jj] = 0.0f;

    #pragma unroll 4
    for (int k = 0; k < H; ++k) {
        float4 wv = *(const float4*)(eW2 + (size_t)k * H + 4 * cc);
        #pragma unroll
        for (int q = 0; q < 4; ++q) {
            float a = buf_s[(ceb + 8 * q) * H + k];
            a2[q][0] += a * wv.x; a2[q][1] += a * wv.y;
            a2[q][2] += a * wv.z; a2[q][3] += a * wv.w;
        }
    }

    // bias + LN + SiLU -> edge_feat (registers first; buf_s still being read by others)
    float ef[4][4];
    {
        float4 bv  = *(const float4*)(eb2 + 4 * cc);
        float4 gv  = *(const float4*)(eg2 + 4 * cc);
        float4 bev = *(const float4*)(ebe2 + 4 * cc);
        #pragma unroll
        for (int q = 0; q < 4; ++q) {
            float x0 = a2[q][0] + bv.x, x1 = a2[q][1] + bv.y;
            float x2 = a2[q][2] + bv.z, x3 = a2[q][3] + bv.w;
            float s  = x0 + x1 + x2 + x3;
            float ss = x0 * x0 + x1 * x1 + x2 * x2 + x3 * x3;
            #pragma unroll
            for (int m = 1; m <= 16; m <<= 1) {
                s  += __shfl_xor(s, m, 64);
                ss += __shfl_xor(ss, m, 64);
            }
            float mu   = s * (1.0f / 128.0f);
            float var  = ss * (1.0f / 128.0f) - mu * mu;
            float rstd = rsqrtf(var + 1e-5f);
            ef[q][0] = silu_f((x0 - mu) * rstd * gv.x + bev.x);
            ef[q][1] = silu_f((x1 - mu) * rstd * gv.y + bev.y);
            ef[q][2] = silu_f((x2 - mu) * rstd * gv.z + bev.z);
            ef[q][3] = silu_f((x3 - mu) * rstd * gv.w + bev.w);
        }
    }
    __syncthreads();
    #pragma unroll
    for (int q = 0; q < 4; ++q) {
        float* dst = &buf_s[(ceb + 8 * q) * H + 4 * cc];
        dst[0] = ef[q][0]; dst[1] = ef[q][1]; dst[2] = ef[q][2]; dst[3] = ef[q][3];
    }
    __syncthreads();

    // ---- GEMM3: edge_feat @ cW1, LN, SiLU, dot cW2 -> cm ----
    float a3[4][4];
    #pragma unroll
    for (int q = 0; q < 4; ++q)
        for (int jj = 0; jj < 4; ++jj) a3[q][jj] = 0.0f;

    #pragma unroll 4
    for (int k = 0; k < H; ++k) {
        float4 wv = *(const float4*)(cW1 + (size_t)k * H + 4 * cc);
        #pragma unroll
        for (int q = 0; q < 4; ++q) {
            float a = buf_s[(ceb + 8 * q) * H + k];
            a3[q][0] += a * wv.x; a3[q][1] += a * wv.y;
            a3[q][2] += a * wv.z; a3[q][3] += a * wv.w;
        }
    }

    float cmv[4];
    {
        float4 bv  = *(const float4*)(cb1 + 4 * cc);
        float4 gv  = *(const float4*)(cg1 + 4 * cc);
        float4 bev = *(const float4*)(cbe1 + 4 * cc);
        float4 w2v = *(const float4*)(cW2 + 4 * cc);
        #pragma unroll
        for (int q = 0; q < 4; ++q) {
            float x0 = a3[q][0] + bv.x, x1 = a3[q][1] + bv.y;
            float x2 = a3[q][2] + bv.z, x3 = a3[q][3] + bv.w;
            float s  = x0 + x1 + x2 + x3;
            float ss = x0 * x0 + x1 * x1 + x2 * x2 + x3 * x3;
            #pragma unroll
            for (int m = 1; m <= 16; m <<= 1) {
                s  += __shfl_xor(s, m, 64);
                ss += __shfl_xor(ss, m, 64);
            }
            float mu   = s * (1.0f / 128.0f);
            float var  = ss * (1.0f / 128.0f) - mu * mu;
            float rstd = rsqrtf(var + 1e-5f);
            float p0 = silu_f((x0 - mu) * rstd * gv.x + bev.x);
            float p1 = silu_f((x1 - mu) * rstd * gv.y + bev.y);
            float p2 = silu_f((x2 - mu) * rstd * gv.z + bev.z);
            float p3 = silu_f((x3 - mu) * rstd * gv.w + bev.w);
            float part = p0 * w2v.x + p1 * w2v.y + p2 * w2v.z + p3 * w2v.w;
            #pragma unroll
            for (int m = 1; m <= 16; m <<= 1) part += __shfl_xor(part, m, 64);
            cmv[q] = part;
        }
    }

    // ---- coord atomics: lanes cc<3 handle x/y/z per edge ----
    if (cc < 3) {
        #pragma unroll
        for (int q = 0; q < 4; ++q) {
            int le = ceb + 8 * q;
            int ge = blockIdx.x * TE + le;
            if (ge < E) {
                float tr = cd_s[le * 3 + cc] * cmv[q];
                atomicAdd(&coord_out[(size_t)row_s[le] * 3 + cc], tr);
            }
        }
    }

    // ---- agg atomics: edge_feat scatter-add ----
    for (int idx = t; idx < TE * H; idx += 256) {
        int le = idx >> 7, c = idx & (H - 1);
        int ge = blockIdx.x * TE + le;
        if (ge < E)
            atomicAdd(&agg[(size_t)row_s[le] * H + c], buf_s[le * H + c]);
    }
}

// -------------------- node kernel --------------------
__global__ __launch_bounds__(256) void node_kernel(
    const float* __restrict__ h, const float* __restrict__ agg,
    const float* __restrict__ nW1, const float* __restrict__ nb1,
    const float* __restrict__ ng1, const float* __restrict__ nbe1,
    const float* __restrict__ nW2, const float* __restrict__ nb2,
    float* __restrict__ out, int N)
{
    __shared__ float nin_s[TN * 256];  // 32 KB
    __shared__ float buf_s[TN * H];    // 16 KB

    const int t = threadIdx.x;
    {
        const int e = t >> 3, j = t & 7;
        int gn = blockIdx.x * TN + e;
        int gnc = (gn < N) ? gn : (N - 1);
        const float4* hr = (const float4*)(h + (size_t)gnc * H);
        const float4* ar = (const float4*)(agg + (size_t)gnc * H);
        #pragma unroll
        for (int i = 0; i < 4; ++i) {
            *(float4*)&nin_s[e * 256 + 4 * (j + 8 * i)]     = hr[j + 8 * i];
            *(float4*)&nin_s[e * 256 + H + 4 * (j + 8 * i)] = ar[j + 8 * i];
        }
    }
    __syncthreads();

    const int cc = t & 31, ceb = t >> 5;

    float acc[4][4];
    #pragma unroll
    for (int q = 0; q < 4; ++q)
        for (int jj = 0; jj < 4; ++jj) acc[q][jj] = 0.0f;

    #pragma unroll 2
    for (int k = 0; k < 2 * H; ++k) {
        float4 wv = *(const float4*)(nW1 + (size_t)k * H + 4 * cc);
        #pragma unroll
        for (int q = 0; q < 4; ++q) {
            float a = nin_s[(ceb + 8 * q) * 256 + k];
            acc[q][0] += a * wv.x; acc[q][1] += a * wv.y;
            acc[q][2] += a * wv.z; acc[q][3] += a * wv.w;
        }
    }

    {
        float4 bv  = *(const float4*)(nb1 + 4 * cc);
        float4 gv  = *(const float4*)(ng1 + 4 * cc);
        float4 bev = *(const float4*)(nbe1 + 4 * cc);
        #pragma unroll
        for (int q = 0; q < 4; ++q) {
            float x0 = acc[q][0] + bv.x, x1 = acc[q][1] + bv.y;
            float x2 = acc[q][2] + bv.z, x3 = acc[q][3] + bv.w;
            float s  = x0 + x1 + x2 + x3;
            float ss = x0 * x0 + x1 * x1 + x2 * x2 + x3 * x3;
            #pragma unroll
            for (int m = 1; m <= 16; m <<= 1) {
                s  += __shfl_xor(s, m, 64);
                ss += __shfl_xor(ss, m, 64);
            }
            float mu   = s * (1.0f / 128.0f);
            float var  = ss * (1.0f / 128.0f) - mu * mu;
            float rstd = rsqrtf(var + 1e-5f);
            float* dst = &buf_s[(ceb + 8 * q) * H + 4 * cc];
            dst[0] = silu_f((x0 - mu) * rstd * gv.x + bev.x);
            dst[1] = silu_f((x1 - mu) * rstd * gv.y + bev.y);
            dst[2] = silu_f((x2 - mu) * rstd * gv.z + bev.z);
            dst[3] = silu_f((x3 - mu) * rstd * gv.w + bev.w);
        }
    }
    __syncthreads();

    float a2[4][4];
    #pragma unroll
    for (int q = 0; q < 4; ++q)
        for (int jj = 0; jj < 4; ++jj) a2[q][jj] = 0.0f;

    #pragma unroll 4
    for (int k = 0; k < H; ++k) {
        float4 wv = *(const float4*)(nW2 + (size_t)k * H + 4 * cc);
        #pragma unroll
        for (int q = 0; q < 4; ++q) {
            float a = buf_s[(ceb + 8 * q) * H + k];
            a2[q][0] += a * wv.x; a2[q][1] += a * wv.y;
            a2[q][2] += a * wv.z; a2[q][3] += a * wv.w;
        }
    }

    {
        float4 bv = *(const float4*)(nb2 + 4 * cc);
        #pragma unroll
        for (int q = 0; q < 4; ++q) {
            int gn = blockIdx.x * TN + (ceb + 8 * q);
            if (gn < N) {
                float4 hv = *(const float4*)(h + (size_t)gn * H + 4 * cc);
                float4 o;
                o.x = a2[q][0] + bv.x + hv.x;
                o.y = a2[q][1] + bv.y + hv.y;
                o.z = a2[q][2] + bv.z + hv.z;
                o.w = a2[q][3] + bv.w + hv.w;
                *(float4*)(out + (size_t)gn * H + 4 * cc) = o;
            }
        }
    }
}

// -------------------- launch --------------------
extern "C" void kernel_launch(void* const* d_in, const int* in_sizes, int n_in,
                              void* d_out, int out_size, void* d_ws, size_t ws_size,
                              hipStream_t stream) {
    const float* h     = (const float*)d_in[0];
    const int*   ei    = (const int*)d_in[1];
    const float* coord = (const float*)d_in[2];
    const float* eattr = (const float*)d_in[3];
    const float* eW1   = (const float*)d_in[4];
    const float* eb1   = (const float*)d_in[5];
    const float* eg1   = (const float*)d_in[6];
    const float* ebe1  = (const float*)d_in[7];
    const float* eW2   = (const float*)d_in[8];
    const float* eb2   = (const float*)d_in[9];
    const float* eg2   = (const float*)d_in[10];
    const float* ebe2  = (const float*)d_in[11];
    const float* nW1   = (const float*)d_in[12];
    const float* nb1   = (const float*)d_in[13];
    const float* ng1   = (const float*)d_in[14];
    const float* nbe1  = (const float*)d_in[15];
    const float* nW2   = (const float*)d_in[16];
    const float* nb2   = (const float*)d_in[17];
    const float* cW1   = (const float*)d_in[18];
    const float* cb1   = (const float*)d_in[19];
    const float* cg1   = (const float*)d_in[20];
    const float* cbe1  = (const float*)d_in[21];
    const float* cW2   = (const float*)d_in[22];

    const int N = in_sizes[0] / H;
    const int E = in_sizes[1] / 2;

    float* out       = (float*)d_out;
    float* coord_out = out + (size_t)N * H;
    float* agg       = (float*)d_ws;   // N*H floats

    hipMemsetAsync(agg, 0, (size_t)N * H * sizeof(float), stream);
    hipMemcpyAsync(coord_out, coord, (size_t)N * 3 * sizeof(float),
                   hipMemcpyDeviceToDevice, stream);

    edge_kernel<<<(E + TE - 1) / TE, 256, 0, stream>>>(
        h, ei, coord, eattr,
        eW1, eb1, eg1, ebe1, eW2, eb2, eg2, ebe2,
        cW1, cb1, cg1, cbe1, cW2,
        agg, coord_out, E);

    node_kernel<<<(N + TN - 1) / TN, 256, 0, stream>>>(
        h, agg, nW1, nb1, ng1, nbe1, nW2, nb2, out, N);
}

// Round 2
// 745.699 us; speedup vs baseline: 1.4595x; 1.4595x over previous
//
#include <hip/hip_runtime.h>
#include <hip/hip_bf16.h>
#include <math.h>

#define H 128
#define KP1 288      // padded K for GEMM1 (258 -> 288 = 9 k-blocks of 32)
#define TEB 64       // edges per block
#define TN 32        // nodes per block (node kernel)

typedef __attribute__((ext_vector_type(8))) short bf16x8;
typedef __attribute__((ext_vector_type(4))) float f32x4;

__device__ __forceinline__ float silu_f(float x) { return x / (1.0f + __expf(-x)); }

__device__ __forceinline__ unsigned short f2bf(float f) {
    unsigned int u = __float_as_uint(f);
    unsigned int r = u + 0x7FFFu + ((u >> 16) & 1u);
    return (unsigned short)(r >> 16);
}

// -------------------- weight prep: W[K][128] fp32 -> Wt[128][Kp] bf16 (zero-padded) ------
__global__ void prep_wt(const float* __restrict__ W, unsigned short* __restrict__ Wt,
                        int K, int Kp) {
    int n = blockIdx.y;
    int k = blockIdx.x * 256 + threadIdx.x;
    if (k < Kp) Wt[(size_t)n * Kp + k] = (k < K) ? f2bf(W[(size_t)k * H + n]) : (unsigned short)0;
}

// -------------------- edge kernel (MFMA bf16) --------------------
// LDS: A1 bf16 [36 oct][64 m][8] = 36864 B; A2/A3 alias A1 (per-wave 4096 B regions);
// cd_s / row_s after 36864.
#define SMEM_BYTES (36864 + 64 * 3 * 4 + 64 * 4)

__global__ __launch_bounds__(256) void edge_kernel(
    const float* __restrict__ h, const int* __restrict__ ei,
    const float* __restrict__ coord, const float* __restrict__ eattr,
    const unsigned short* __restrict__ eW1t,
    const float* __restrict__ eb1, const float* __restrict__ eg1, const float* __restrict__ ebe1,
    const unsigned short* __restrict__ eW2t,
    const float* __restrict__ eb2, const float* __restrict__ eg2, const float* __restrict__ ebe2,
    const unsigned short* __restrict__ cW1t,
    const float* __restrict__ cb1, const float* __restrict__ cg1, const float* __restrict__ cbe1,
    const float* __restrict__ cW2,
    float* __restrict__ agg, float* __restrict__ coord_out, int E)
{
    __shared__ char smem[SMEM_BYTES];
    unsigned short* A1   = (unsigned short*)smem;
    float*          cd_s = (float*)(smem + 36864);
    int*            row_s = (int*)(smem + 36864 + 64 * 3 * 4);

    const int t    = threadIdx.x;
    const int lane = t & 63, wave = t >> 6;
    const int l15  = lane & 15, quad = lane >> 4;

    // ---- stage A1: 4 threads per edge; bf16 convert on the fly ----
    {
        const int m = t >> 2, part = t & 3;
        int ge  = blockIdx.x * TEB + m;
        int gec = (ge < E) ? ge : 0;
        int row = ei[gec], colv = ei[E + gec];
        const float* src = ((part < 2) ? (h + (size_t)row * H) : (h + (size_t)colv * H))
                           + (part & 1) * 64;
        const int baseoct = part * 8;
        #pragma unroll
        for (int o = 0; o < 8; ++o) {
            float4 f0 = ((const float4*)src)[2 * o];
            float4 f1 = ((const float4*)src)[2 * o + 1];
            union { bf16x8 v; unsigned short u[8]; } pk;
            pk.u[0] = f2bf(f0.x); pk.u[1] = f2bf(f0.y); pk.u[2] = f2bf(f0.z); pk.u[3] = f2bf(f0.w);
            pk.u[4] = f2bf(f1.x); pk.u[5] = f2bf(f1.y); pk.u[6] = f2bf(f1.z); pk.u[7] = f2bf(f1.w);
            *(bf16x8*)&A1[((baseoct + o) * TEB + m) * 8] = pk.v;
        }
        if (part == 0) {
            row_s[m] = row;
            float dx = coord[row * 3 + 0] - coord[colv * 3 + 0];
            float dy = coord[row * 3 + 1] - coord[colv * 3 + 1];
            float dz = coord[row * 3 + 2] - coord[colv * 3 + 2];
            float radial = dx * dx + dy * dy + dz * dz;
            float inv = 1.0f / (sqrtf(radial + 1e-8f) + 1.0f);
            cd_s[m * 3 + 0] = dx * inv;
            cd_s[m * 3 + 1] = dy * inv;
            cd_s[m * 3 + 2] = dz * inv;
            union { bf16x8 v; unsigned short u[8]; } pk;
            #pragma unroll
            for (int i = 0; i < 8; ++i) pk.u[i] = 0;
            pk.u[0] = f2bf(radial);
            pk.u[1] = f2bf((ge < E) ? eattr[ge] : 0.0f);
            *(bf16x8*)&A1[(32 * TEB + m) * 8] = pk.v;
            #pragma unroll
            for (int i = 0; i < 8; ++i) pk.u[i] = 0;
            *(bf16x8*)&A1[(33 * TEB + m) * 8] = pk.v;
            *(bf16x8*)&A1[(34 * TEB + m) * 8] = pk.v;
            *(bf16x8*)&A1[(35 * TEB + m) * 8] = pk.v;
        }
    }
    __syncthreads();

    const int mrow = wave * 16 + l15;          // A-fragment row this lane reads
    const int col  = l15;                      // + nt*16 per tile

    f32x4 acc[8];
    #pragma unroll
    for (int nt = 0; nt < 8; ++nt) acc[nt] = (f32x4){0.f, 0.f, 0.f, 0.f};

    // ---- GEMM1: [64x288] @ eW1t ----
    for (int kb = 0; kb < 9; ++kb) {
        bf16x8 af = *(const bf16x8*)&A1[((kb * 4 + quad) * TEB + mrow) * 8];
        const unsigned short* bp = eW1t + (size_t)l15 * KP1 + kb * 32 + quad * 8;
        #pragma unroll
        for (int nt = 0; nt < 8; ++nt) {
            bf16x8 bf = *(const bf16x8*)(bp + (size_t)nt * 16 * KP1);
            acc[nt] = __builtin_amdgcn_mfma_f32_16x16x32_bf16(af, bf, acc[nt], 0, 0, 0);
        }
    }
    __syncthreads();   // all waves done reading A1 before A2 overwrites it

    unsigned short* A2w = (unsigned short*)smem + wave * 2048;          // 4096 B / wave
    unsigned short* A3w = (unsigned short*)smem + 8192 + wave * 2048;   // offset 16384 B

    // ---- epilogue 1: bias + LN + SiLU -> A2 (bf16) ----
    {
        float s[4] = {0, 0, 0, 0}, ss[4] = {0, 0, 0, 0};
        #pragma unroll
        for (int nt = 0; nt < 8; ++nt) {
            float b = eb1[nt * 16 + col];
            #pragma unroll
            for (int r = 0; r < 4; ++r) {
                float x = acc[nt][r] + b;
                acc[nt][r] = x;
                s[r] += x; ss[r] += x * x;
            }
        }
        #pragma unroll
        for (int msk = 1; msk <= 8; msk <<= 1) {
            #pragma unroll
            for (int r = 0; r < 4; ++r) {
                s[r]  += __shfl_xor(s[r],  msk, 64);
                ss[r] += __shfl_xor(ss[r], msk, 64);
            }
        }
        float mu[4], rstd[4];
        #pragma unroll
        for (int r = 0; r < 4; ++r) {
            mu[r] = s[r] * (1.0f / 128.0f);
            float var = ss[r] * (1.0f / 128.0f) - mu[r] * mu[r];
            rstd[r] = rsqrtf(var + 1e-5f);
        }
        #pragma unroll
        for (int nt = 0; nt < 8; ++nt) {
            float g = eg1[nt * 16 + col], be = ebe1[nt * 16 + col];
            int oct = nt * 2 + (l15 >> 3), j = l15 & 7;
            #pragma unroll
            for (int r = 0; r < 4; ++r) {
                float y = silu_f((acc[nt][r] - mu[r]) * rstd[r] * g + be);
                A2w[((oct * 16 + (quad * 4 + r)) * 8) + j] = f2bf(y);
            }
        }
    }

    // ---- GEMM2: [16x128] @ eW2t (per-wave A2) ----
    #pragma unroll
    for (int nt = 0; nt < 8; ++nt) acc[nt] = (f32x4){0.f, 0.f, 0.f, 0.f};
    for (int kb = 0; kb < 4; ++kb) {
        bf16x8 af = *(const bf16x8*)&A2w[((kb * 4 + quad) * 16 + l15) * 8];
        const unsigned short* bp = eW2t + (size_t)l15 * H + kb * 32 + quad * 8;
        #pragma unroll
        for (int nt = 0; nt < 8; ++nt) {
            bf16x8 bf = *(const bf16x8*)(bp + (size_t)nt * 16 * H);
            acc[nt] = __builtin_amdgcn_mfma_f32_16x16x32_bf16(af, bf, acc[nt], 0, 0, 0);
        }
    }

    // ---- epilogue 2: bias + LN + SiLU = edge_feat; atomics to agg + bf16 to A3 ----
    {
        float s[4] = {0, 0, 0, 0}, ss[4] = {0, 0, 0, 0};
        #pragma unroll
        for (int nt = 0; nt < 8; ++nt) {
            float b = eb2[nt * 16 + col];
            #pragma unroll
            for (int r = 0; r < 4; ++r) {
                float x = acc[nt][r] + b;
                acc[nt][r] = x;
                s[r] += x; ss[r] += x * x;
            }
        }
        #pragma unroll
        for (int msk = 1; msk <= 8; msk <<= 1) {
            #pragma unroll
            for (int r = 0; r < 4; ++r) {
                s[r]  += __shfl_xor(s[r],  msk, 64);
                ss[r] += __shfl_xor(ss[r], msk, 64);
            }
        }
        float mu[4], rstd[4];
        #pragma unroll
        for (int r = 0; r < 4; ++r) {
            mu[r] = s[r] * (1.0f / 128.0f);
            float var = ss[r] * (1.0f / 128.0f) - mu[r] * mu[r];
            rstd[r] = rsqrtf(var + 1e-5f);
        }
        #pragma unroll
        for (int nt = 0; nt < 8; ++nt) {
            float g = eg2[nt * 16 + col], be = ebe2[nt * 16 + col];
            int oct = nt * 2 + (l15 >> 3), j = l15 & 7;
            #pragma unroll
            for (int r = 0; r < 4; ++r) {
                float ef = silu_f((acc[nt][r] - mu[r]) * rstd[r] * g + be);
                A3w[((oct * 16 + (quad * 4 + r)) * 8) + j] = f2bf(ef);
                int m  = wave * 16 + quad * 4 + r;
                int ge = blockIdx.x * TEB + m;
                if (ge < E)
                    atomicAdd(&agg[(size_t)row_s[m] * H + nt * 16 + col], ef);
            }
        }
    }

    // ---- GEMM3: edge_feat @ cW1t ----
    #pragma unroll
    for (int nt = 0; nt < 8; ++nt) acc[nt] = (f32x4){0.f, 0.f, 0.f, 0.f};
    for (int kb = 0; kb < 4; ++kb) {
        bf16x8 af = *(const bf16x8*)&A3w[((kb * 4 + quad) * 16 + l15) * 8];
        const unsigned short* bp = cW1t + (size_t)l15 * H + kb * 32 + quad * 8;
        #pragma unroll
        for (int nt = 0; nt < 8; ++nt) {
            bf16x8 bf = *(const bf16x8*)(bp + (size_t)nt * 16 * H);
            acc[nt] = __builtin_amdgcn_mfma_f32_16x16x32_bf16(af, bf, acc[nt], 0, 0, 0);
        }
    }

    // ---- epilogue 3: bias + LN + SiLU, dot cW2 -> cm; coord atomics ----
    {
        float s[4] = {0, 0, 0, 0}, ss[4] = {0, 0, 0, 0};
        #pragma unroll
        for (int nt = 0; nt < 8; ++nt) {
            float b = cb1[nt * 16 + col];
            #pragma unroll
            for (int r = 0; r < 4; ++r) {
                float x = acc[nt][r] + b;
                acc[nt][r] = x;
                s[r] += x; ss[r] += x * x;
            }
        }
        #pragma unroll
        for (int msk = 1; msk <= 8; msk <<= 1) {
            #pragma unroll
            for (int r = 0; r < 4; ++r) {
                s[r]  += __shfl_xor(s[r],  msk, 64);
                ss[r] += __shfl_xor(ss[r], msk, 64);
            }
        }
        float cm[4] = {0, 0, 0, 0};
        float mu[4], rstd[4];
        #pragma unroll
        for (int r = 0; r < 4; ++r) {
            mu[r] = s[r] * (1.0f / 128.0f);
            float var = ss[r] * (1.0f / 128.0f) - mu[r] * mu[r];
            rstd[r] = rsqrtf(var + 1e-5f);
        }
        #pragma unroll
        for (int nt = 0; nt < 8; ++nt) {
            float g = cg1[nt * 16 + col], be = cbe1[nt * 16 + col];
            float w2 = cW2[nt * 16 + col];
            #pragma unroll
            for (int r = 0; r < 4; ++r) {
                float p = silu_f((acc[nt][r] - mu[r]) * rstd[r] * g + be);
                cm[r] += p * w2;
            }
        }
        #pragma unroll
        for (int msk = 1; msk <= 8; msk <<= 1) {
            #pragma unroll
            for (int r = 0; r < 4; ++r) cm[r] += __shfl_xor(cm[r], msk, 64);
        }
        if (l15 < 3) {
            #pragma unroll
            for (int r = 0; r < 4; ++r) {
                int m  = wave * 16 + quad * 4 + r;
                int ge = blockIdx.x * TEB + m;
                if (ge < E)
                    atomicAdd(&coord_out[(size_t)row_s[m] * 3 + l15],
                              cd_s[m * 3 + l15] * cm[r]);
            }
        }
    }
}

// -------------------- node kernel (fp32, unchanged from R1) --------------------
__global__ __launch_bounds__(256) void node_kernel(
    const float* __restrict__ h, const float* __restrict__ agg,
    const float* __restrict__ nW1, const float* __restrict__ nb1,
    const float* __restrict__ ng1, const float* __restrict__ nbe1,
    const float* __restrict__ nW2, const float* __restrict__ nb2,
    float* __restrict__ out, int N)
{
    __shared__ float nin_s[TN * 256];
    __shared__ float buf_s[TN * H];

    const int t = threadIdx.x;
    {
        const int e = t >> 3, j = t & 7;
        int gn = blockIdx.x * TN + e;
        int gnc = (gn < N) ? gn : (N - 1);
        const float4* hr = (const float4*)(h + (size_t)gnc * H);
        const float4* ar = (const float4*)(agg + (size_t)gnc * H);
        #pragma unroll
        for (int i = 0; i < 4; ++i) {
            *(float4*)&nin_s[e * 256 + 4 * (j + 8 * i)]     = hr[j + 8 * i];
            *(float4*)&nin_s[e * 256 + H + 4 * (j + 8 * i)] = ar[j + 8 * i];
        }
    }
    __syncthreads();

    const int cc = t & 31, ceb = t >> 5;

    float acc[4][4];
    #pragma unroll
    for (int q = 0; q < 4; ++q)
        for (int jj = 0; jj < 4; ++jj) acc[q][jj] = 0.0f;

    #pragma unroll 2
    for (int k = 0; k < 2 * H; ++k) {
        float4 wv = *(const float4*)(nW1 + (size_t)k * H + 4 * cc);
        #pragma unroll
        for (int q = 0; q < 4; ++q) {
            float a = nin_s[(ceb + 8 * q) * 256 + k];
            acc[q][0] += a * wv.x; acc[q][1] += a * wv.y;
            acc[q][2] += a * wv.z; acc[q][3] += a * wv.w;
        }
    }

    {
        float4 bv  = *(const float4*)(nb1 + 4 * cc);
        float4 gv  = *(const float4*)(ng1 + 4 * cc);
        float4 bev = *(const float4*)(nbe1 + 4 * cc);
        #pragma unroll
        for (int q = 0; q < 4; ++q) {
            float x0 = acc[q][0] + bv.x, x1 = acc[q][1] + bv.y;
            float x2 = acc[q][2] + bv.z, x3 = acc[q][3] + bv.w;
            float s  = x0 + x1 + x2 + x3;
            float ss = x0 * x0 + x1 * x1 + x2 * x2 + x3 * x3;
            #pragma unroll
            for (int m = 1; m <= 16; m <<= 1) {
                s  += __shfl_xor(s, m, 64);
                ss += __shfl_xor(ss, m, 64);
            }
            float mu   = s * (1.0f / 128.0f);
            float var  = ss * (1.0f / 128.0f) - mu * mu;
            float rstd = rsqrtf(var + 1e-5f);
            float* dst = &buf_s[(ceb + 8 * q) * H + 4 * cc];
            dst[0] = silu_f((x0 - mu) * rstd * gv.x + bev.x);
            dst[1] = silu_f((x1 - mu) * rstd * gv.y + bev.y);
            dst[2] = silu_f((x2 - mu) * rstd * gv.z + bev.z);
            dst[3] = silu_f((x3 - mu) * rstd * gv.w + bev.w);
        }
    }
    __syncthreads();

    float a2[4][4];
    #pragma unroll
    for (int q = 0; q < 4; ++q)
        for (int jj = 0; jj < 4; ++jj) a2[q][jj] = 0.0f;

    #pragma unroll 4
    for (int k = 0; k < H; ++k) {
        float4 wv = *(const float4*)(nW2 + (size_t)k * H + 4 * cc);
        #pragma unroll
        for (int q = 0; q < 4; ++q) {
            float a = buf_s[(ceb + 8 * q) * H + k];
            a2[q][0] += a * wv.x; a2[q][1] += a * wv.y;
            a2[q][2] += a * wv.z; a2[q][3] += a * wv.w;
        }
    }

    {
        float4 bv = *(const float4*)(nb2 + 4 * cc);
        #pragma unroll
        for (int q = 0; q < 4; ++q) {
            int gn = blockIdx.x * TN + (ceb + 8 * q);
            if (gn < N) {
                float4 hv = *(const float4*)(h + (size_t)gn * H + 4 * cc);
                float4 o;
                o.x = a2[q][0] + bv.x + hv.x;
                o.y = a2[q][1] + bv.y + hv.y;
                o.z = a2[q][2] + bv.z + hv.z;
                o.w = a2[q][3] + bv.w + hv.w;
                *(float4*)(out + (size_t)gn * H + 4 * cc) = o;
            }
        }
    }
}

// -------------------- launch --------------------
extern "C" void kernel_launch(void* const* d_in, const int* in_sizes, int n_in,
                              void* d_out, int out_size, void* d_ws, size_t ws_size,
                              hipStream_t stream) {
    const float* h     = (const float*)d_in[0];
    const int*   ei    = (const int*)d_in[1];
    const float* coord = (const float*)d_in[2];
    const float* eattr = (const float*)d_in[3];
    const float* eW1   = (const float*)d_in[4];
    const float* eb1   = (const float*)d_in[5];
    const float* eg1   = (const float*)d_in[6];
    const float* ebe1  = (const float*)d_in[7];
    const float* eW2   = (const float*)d_in[8];
    const float* eb2   = (const float*)d_in[9];
    const float* eg2   = (const float*)d_in[10];
    const float* ebe2  = (const float*)d_in[11];
    const float* nW1   = (const float*)d_in[12];
    const float* nb1   = (const float*)d_in[13];
    const float* ng1   = (const float*)d_in[14];
    const float* nbe1  = (const float*)d_in[15];
    const float* nW2   = (const float*)d_in[16];
    const float* nb2   = (const float*)d_in[17];
    const float* cW1   = (const float*)d_in[18];
    const float* cb1   = (const float*)d_in[19];
    const float* cg1   = (const float*)d_in[20];
    const float* cbe1  = (const float*)d_in[21];
    const float* cW2   = (const float*)d_in[22];

    const int N = in_sizes[0] / H;
    const int E = in_sizes[1] / 2;

    float* out       = (float*)d_out;
    float* coord_out = out + (size_t)N * H;

    float* agg = (float*)d_ws;                               // N*H fp32
    unsigned short* eW1t = (unsigned short*)((char*)d_ws + (size_t)N * H * sizeof(float));
    unsigned short* eW2t = eW1t + (size_t)H * KP1;
    unsigned short* cW1t = eW2t + (size_t)H * H;

    hipMemsetAsync(agg, 0, (size_t)N * H * sizeof(float), stream);
    hipMemcpyAsync(coord_out, coord, (size_t)N * 3 * sizeof(float),
                   hipMemcpyDeviceToDevice, stream);

    prep_wt<<<dim3((KP1 + 255) / 256, H), 256, 0, stream>>>(eW1, eW1t, 258, KP1);
    prep_wt<<<dim3(1, H), 256, 0, stream>>>(eW2, eW2t, H, H);
    prep_wt<<<dim3(1, H), 256, 0, stream>>>(cW1, cW1t, H, H);

    edge_kernel<<<(E + TEB - 1) / TEB, 256, 0, stream>>>(
        h, ei, coord, eattr,
        eW1t, eb1, eg1, ebe1,
        eW2t, eb2, eg2, ebe2,
        cW1t, cb1, cg1, cbe1, cW2,
        agg, coord_out, E);

    node_kernel<<<(N + TN - 1) / TN, 256, 0, stream>>>(
        h, agg, nW1, nb1, ng1, nbe1, nW2, nb2, out, N);
}